// Round 4
// baseline (119.770 us; speedup 1.0000x reference)
//
#include <hip/hip_runtime.h>
#include <math.h>

#define NJ 8         // odd powers x^1..x^15
#define DEG 15
#define X0f 3.0f

struct Poly { float c[NJ]; };

#define FMA4(A,S,W) do { (A).x = fmaf((S),(W).x,(A).x); (A).y = fmaf((S),(W).y,(A).y); \
                         (A).z = fmaf((S),(W).z,(A).z); (A).w = fmaf((S),(W).w,(A).w); } while(0)

// ---------------- K0: repack weights ----------------
// WcT[i][m 0..463][32]  (m = seg*152+e', zero pads; rows 456..463 zero)
// W1T[m 0..455][128]
// Wt0[304][152], Wt1[76][152], Wt2[36][152]  (d-major, e-padded, zero pads)
__global__ __launch_bounds__(256) void k_repack(
    const float* __restrict__ Wc, const float* __restrict__ W1,
    const float* __restrict__ eW0, const float* __restrict__ eW1, const float* __restrict__ eW2,
    float* __restrict__ WcT, float* __restrict__ W1T,
    float* __restrict__ Wt0, float* __restrict__ Wt1, float* __restrict__ Wt2) {
    int tid = blockIdx.x * 256 + threadIdx.x;
    int stride = gridDim.x * 256;
    for (int idx = tid; idx < 3 * 464 * 32; idx += stride) {
        int i = idx / (464 * 32); int rem = idx - i * 464 * 32;
        int m = rem >> 5, h = rem & 31;
        float v = 0.f;
        if (m < 456) {
            int seg = m / 152, e = m - seg * 152;
            if (e < 150) v = Wc[((size_t)i * 32 + h) * 450 + seg * 150 + e];
        }
        WcT[idx] = v;
    }
    for (int idx = tid; idx < 456 * 128; idx += stride) {
        int m = idx >> 7, k = idx & 127;
        int seg = m / 152, e = m - seg * 152;
        W1T[idx] = (e < 150) ? W1[k * 450 + seg * 150 + e] : 0.f;
    }
    for (int idx = tid; idx < 304 * 152; idx += stride) {
        int d = idx / 152, e = idx - d * 152;
        Wt0[idx] = (d < 300 && e < 150) ? eW0[e * 300 + d] : 0.f;
    }
    for (int idx = tid; idx < 76 * 152; idx += stride) {
        int d = idx / 152, e = idx - d * 152;
        Wt1[idx] = (d < 74 && e < 150) ? eW1[e * 74 + d] : 0.f;
    }
    for (int idx = tid; idx < 36 * 152; idx += stride) {
        int d = idx / 152, e = idx - d * 152;
        Wt2[idx] = (d < 35 && e < 150) ? eW2[e * 35 + d] : 0.f;
    }
}

// ---------------- K1: fully fused, weight-loads amortized over all 8 b ----------------
__global__ __launch_bounds__(768, 1) void k_fused(
    const float* __restrict__ x0, const float* __restrict__ x1, const float* __restrict__ x2,
    const float* __restrict__ eb0, const float* __restrict__ eb1, const float* __restrict__ eb2,
    const float* __restrict__ Wt0, const float* __restrict__ Wt1, const float* __restrict__ Wt2,
    const float* __restrict__ WcT,
    const float* __restrict__ affw, const float* __restrict__ Ww, const float* __restrict__ Wh,
    const float* __restrict__ W1T, const float* __restrict__ cb1,
    const float* __restrict__ cW2, const float* __restrict__ cb2,
    float* __restrict__ out, Poly pc) {
    // R: union region. enc: x0 stage [8][304]. M-phase: M[3][8J][8b][36]=6912f.
    // cls: hp[4][8][128]=4096f + hbuf[8][132]=1056f.
    __shared__ __align__(16) float R[6912];
    __shared__ __align__(16) float featf[8 * 468];
    __shared__ __align__(16) float fof[8 * 468];
    __shared__ __align__(16) float wWs[96], wHs[96];
    __shared__ unsigned smaxu[8];

    int tid = threadIdx.x;
    int b0 = blockIdx.x * 8;

    // ---- P0: init + stage x0 ----
    for (int k = tid; k < 8 * 468; k += 768) featf[k] = 0.f;
    if (tid < 8) smaxu[tid] = 0u;
    if (tid < 96) { wWs[tid] = Ww[tid]; wHs[tid] = Wh[tid]; }
    if (tid >= 96 && tid < 144) {            // zero fo segment pads (e=150,151)
        int q = tid - 96; int b = q / 6, r = q - b * 6;
        fof[b * 468 + (r >> 1) * 152 + 150 + (r & 1)] = 0.f;
    }
    for (int idx = tid; idx < 600; idx += 768) {
        int b = idx / 75, q = idx - b * 75;
        ((float4*)(R + b * 304))[q] = ((const float4*)(x0 + (size_t)(b0 + b) * 300))[q];
    }
    __syncthreads();

    // ---- P1: encoders. slot = (seg,e4[,d-half]); 8-lane group shares W (b=lane&7) ----
    {
        int w = tid >> 6, lane = tid & 63, g = lane >> 3, b = lane & 7;
        for (int s = w * 8 + g; s < 152; s += 96) {
            int seg, e4, dlo, dhi, addBias;
            if (s < 76)       { seg = 0; e4 = s >> 1; dlo = (s & 1) * 152; dhi = (s & 1) ? 300 : 152; addBias = !(s & 1); }
            else if (s < 114) { seg = 1; e4 = s - 76;  dlo = 0; dhi = 74; addBias = 1; }
            else              { seg = 2; e4 = s - 114; dlo = 0; dhi = 35; addBias = 1; }
            const float* eb = seg == 0 ? eb0 : seg == 1 ? eb1 : eb2;
            const float4* W4 = (const float4*)(seg == 0 ? Wt0 : seg == 1 ? Wt1 : Wt2) + e4;
            int e = e4 * 4;
            float4 acc = make_float4(0.f, 0.f, 0.f, 0.f);
            if (addBias) {
                acc.x = (e     < 150) ? eb[e]     : 0.f;
                acc.y = (e + 1 < 150) ? eb[e + 1] : 0.f;
                acc.z = (e + 2 < 150) ? eb[e + 2] : 0.f;
                acc.w = (e + 3 < 150) ? eb[e + 3] : 0.f;
            }
            if (seg == 0) {
                const float* xb = R + b * 304;
                #pragma unroll 4
                for (int d = dlo; d < dhi; ++d) { float xv = xb[d]; float4 wv = W4[d * 38]; FMA4(acc, xv, wv); }
            } else if (seg == 1) {
                const float* xb = x1 + (size_t)(b0 + b) * 74;
                #pragma unroll 2
                for (int d = 0; d < 74; ++d) { float xv = xb[d]; float4 wv = W4[d * 38]; FMA4(acc, xv, wv); }
            } else {
                const float* xb = x2 + (size_t)(b0 + b) * 35;
                #pragma unroll 5
                for (int d = 0; d < 35; ++d) { float xv = xb[d]; float4 wv = W4[d * 38]; FMA4(acc, xv, wv); }
            }
            float* dst = featf + b * 468 + seg * 152 + e;
            atomicAdd(dst + 0, acc.x); atomicAdd(dst + 1, acc.y);
            atomicAdd(dst + 2, acc.z); atomicAdd(dst + 3, acc.w);
        }
    }
    __syncthreads();

    // ---- P2a: zero M (overlays R) ----
    for (int k = tid; k < 6912; k += 768) R[k] = 0.f;
    __syncthreads();

    // ---- P2b: M-phase. wave = (i, J-half, c-slice); lane = (hq, b) ----
    {
        int w = tid >> 6;
        int i = w >> 2, jh = (w >> 1) & 1, cs = w & 1;
        int lane = tid & 63, hq = lane & 7, b = lane >> 3;
        float aff = affw[i];
        const float4* Wb4 = (const float4*)WcT + (size_t)i * 3712 + hq;
        const float* fb = featf + b * 468;
        float4 acc[4];
        acc[0] = acc[1] = acc[2] = acc[3] = make_float4(0.f, 0.f, 0.f, 0.f);
        float mx = 0.f;
        int clo = cs * 228;
        #pragma unroll 2
        for (int c = clo; c < clo + 228; ++c) {
            float fv = fb[c];
            float4 wv = Wb4[(size_t)c * 8];
            mx = fmaxf(mx, fabsf(fv));
            float g = aff * fv, g2 = g * g;
            float p0;
            if (jh == 0) p0 = g;
            else { float g4 = g2 * g2; p0 = g4 * g4 * g; }
            float p1 = p0 * g2, p2 = p1 * g2, p3 = p2 * g2;
            FMA4(acc[0], p0, wv); FMA4(acc[1], p1, wv);
            FMA4(acc[2], p2, wv); FMA4(acc[3], p3, wv);
        }
        float* Mb = R + ((i * 8 + jh * 4) * 8 + b) * 36 + hq * 4;
        #pragma unroll
        for (int r = 0; r < 4; ++r) {
            float cJ = pc.c[jh * 4 + r];
            float* p = Mb + r * 288;   // J-stride = 8*36 floats
            atomicAdd(p + 0, acc[r].x * cJ); atomicAdd(p + 1, acc[r].y * cJ);
            atomicAdd(p + 2, acc[r].z * cJ); atomicAdd(p + 3, acc[r].w * cJ);
        }
        if (i == 0 && jh == 0 && hq == 0) atomicMax(&smaxu[b], __float_as_uint(mx));
    }
    __syncthreads();

    // ---- P3: attention epilogue. wave handles 2 (i,b) pairs; lanes = e ----
    {
        int w = tid >> 6, lane = tid & 63;
        #pragma unroll
        for (int pp = 0; pp < 2; ++pp) {
            int pair = w * 2 + pp;
            int i = pair >> 3, b = pair & 7;
            float aff = affw[i];
            float gmax = fabsf(aff) * __uint_as_float(smaxu[b]);
            const float* fb = featf + b * 468;
            const float4* M40 = (const float4*)R + (i * 64 + b) * 9;
            const float4* wW4 = (const float4*)wWs + i * 8;
            const float4* wH4 = (const float4*)wHs + i * 8;
            for (int e = lane; e < 150; e += 64) {
                float s = fb[i * 152 + e];
                float4 a[8];
                if (fabsf(s) * gmax <= X0f) {
                    float s2 = s * s, p = s;
                    #pragma unroll
                    for (int h4 = 0; h4 < 8; ++h4) {
                        float4 m = M40[h4];
                        a[h4].x = m.x * p; a[h4].y = m.y * p; a[h4].z = m.z * p; a[h4].w = m.w * p;
                    }
                    #pragma unroll
                    for (int J = 1; J < NJ; ++J) {
                        p *= s2;
                        const float4* Mj = M40 + J * 72;
                        #pragma unroll
                        for (int h4 = 0; h4 < 8; ++h4) FMA4(a[h4], p, Mj[h4]);
                    }
                } else {
                    #pragma unroll
                    for (int h4 = 0; h4 < 8; ++h4) a[h4] = make_float4(0.f, 0.f, 0.f, 0.f);
                    const float4* Wb4 = (const float4*)WcT + (size_t)i * 3712;
                    for (int c = 0; c < 456; ++c) {
                        float t = tanhf(s * aff * fb[c]);
                        #pragma unroll
                        for (int h4 = 0; h4 < 8; ++h4) FMA4(a[h4], t, Wb4[(size_t)c * 8 + h4]);
                    }
                }
                float o = 0.f;
                #pragma unroll
                for (int h4 = 0; h4 < 8; ++h4) {
                    float4 ww = wW4[h4], wh = wH4[h4], av = a[h4];
                    o = fmaf(fmaxf(fmaf(s, ww.x, av.x), 0.f), wh.x, o);
                    o = fmaf(fmaxf(fmaf(s, ww.y, av.y), 0.f), wh.y, o);
                    o = fmaf(fmaxf(fmaf(s, ww.z, av.z), 0.f), wh.z, o);
                    o = fmaf(fmaxf(fmaf(s, ww.w, av.w), 0.f), wh.w, o);
                }
                fof[b * 468 + i * 152 + e] = o + s;
            }
        }
    }
    __syncthreads();

    // ---- P4: classifier stage 1. wave=(c-slice, k-half); lane=(u->k4, b) ----
    {
        int w = tid >> 6, lane = tid & 63, u = lane & 7, b = lane >> 3;
        if (w < 8) {
            int cs = w & 3, half = w >> 2;
            float4 acc0 = make_float4(0.f, 0.f, 0.f, 0.f), acc1 = acc0;
            const float* fb = fof + b * 468;
            const float4* W14 = (const float4*)W1T + half * 16 + u;
            int clo = cs * 114;
            #pragma unroll 2
            for (int c = clo; c < clo + 114; ++c) {
                float fv = fb[c];
                float4 w0 = W14[(size_t)c * 32];
                float4 w1 = W14[(size_t)c * 32 + 8];
                FMA4(acc0, fv, w0); FMA4(acc1, fv, w1);
            }
            float4* hp = (float4*)R + (cs * 8 + b) * 32 + half * 16 + u;
            hp[0] = acc0; hp[8] = acc1;
        }
    }
    __syncthreads();
    if (tid < 256) {
        int b = tid >> 5, k4 = tid & 31;
        const float4* hp4 = (const float4*)R;
        float4 v  = hp4[(0 * 8 + b) * 32 + k4];
        float4 v1 = hp4[(1 * 8 + b) * 32 + k4];
        float4 v2 = hp4[(2 * 8 + b) * 32 + k4];
        float4 v3 = hp4[(3 * 8 + b) * 32 + k4];
        float4 bias = ((const float4*)cb1)[k4];
        v.x += v1.x + v2.x + v3.x + bias.x;
        v.y += v1.y + v2.y + v3.y + bias.y;
        v.z += v1.z + v2.z + v3.z + bias.z;
        v.w += v1.w + v2.w + v3.w + bias.w;
        ((float4*)(R + 4096))[b * 33 + k4] = v;
    }
    __syncthreads();
    if (tid < 56) {
        int b = tid / 7, o = tid - (tid / 7) * 7;
        const float* hb = R + 4096 + b * 132;
        const float* w2 = cW2 + o * 128;
        float acc = cb2[o];
        #pragma unroll 4
        for (int k = 0; k < 128; ++k) acc = fmaf(hb[k], w2[k], acc);
        out[(size_t)(b0 + b) * 7 + o] = acc;
    }
}

// ---------------- host: Chebyshev fit of tanh on [-3,3], odd monomials ----------------
static void make_poly(float* cf) {
    const double a = 3.0;
    const int NQ = 128;
    const double PI = 3.14159265358979323846;
    double b[DEG + 1];
    for (int k = 0; k <= DEG; ++k) b[k] = 0.0;
    for (int m = 0; m < NQ; ++m) {
        double th = PI * (m + 0.5) / NQ;
        double f = tanh(a * cos(th));
        for (int k = 1; k <= DEG; k += 2)
            b[k] += (2.0 / NQ) * f * cos(k * th);
    }
    double Tp[DEG + 1], Tc[DEG + 1], Tn[DEG + 1], mono[DEG + 1];
    for (int j = 0; j <= DEG; ++j) { Tp[j] = 0; Tc[j] = 0; mono[j] = 0; }
    Tp[0] = 1.0;
    Tc[1] = 1.0;
    for (int j = 0; j <= DEG; ++j) mono[j] += b[1] * Tc[j];
    for (int k = 2; k <= DEG; ++k) {
        for (int j = 0; j <= DEG; ++j) Tn[j] = -Tp[j];
        for (int j = 1; j <= DEG; ++j) Tn[j] += 2.0 * Tc[j - 1];
        for (int j = 0; j <= DEG; ++j) { Tp[j] = Tc[j]; Tc[j] = Tn[j]; }
        if (k & 1) for (int j = 0; j <= DEG; ++j) mono[j] += b[k] * Tc[j];
    }
    for (int J = 0; J < NJ; ++J) {
        int j = 2 * J + 1;
        cf[J] = (float)(mono[j] / pow(a, (double)j));
    }
}

extern "C" void kernel_launch(void* const* d_in, const int* in_sizes, int n_in,
                              void* d_out, int out_size, void* d_ws, size_t ws_size,
                              hipStream_t stream) {
    (void)in_sizes; (void)n_in; (void)out_size; (void)ws_size;
    const float* x0    = (const float*)d_in[0];
    const float* x1    = (const float*)d_in[1];
    const float* x2    = (const float*)d_in[2];
    const float* eW0   = (const float*)d_in[3];
    const float* eb0   = (const float*)d_in[4];
    const float* eW1   = (const float*)d_in[5];
    const float* eb1   = (const float*)d_in[6];
    const float* eW2   = (const float*)d_in[7];
    const float* eb2   = (const float*)d_in[8];
    const float* affw  = (const float*)d_in[9];
    const float* Ww    = (const float*)d_in[10];
    const float* Wc    = (const float*)d_in[11];
    const float* Wh    = (const float*)d_in[12];
    const float* cW1   = (const float*)d_in[13];
    const float* cb1   = (const float*)d_in[14];
    const float* cW2   = (const float*)d_in[15];
    const float* cb2   = (const float*)d_in[16];

    float* ws    = (float*)d_ws;
    float* wsWcT = ws;                 // 3*464*32  = 44544
    float* wsW1T = ws + 44544;         // 456*128   = 58368
    float* wsWt0 = ws + 102912;        // 304*152   = 46208
    float* wsWt1 = ws + 149120;        // 76*152    = 11552
    float* wsWt2 = ws + 160672;        // 36*152    = 5472

    Poly pc;
    make_poly(pc.c);

    k_repack<<<dim3(96), dim3(256), 0, stream>>>(Wc, cW1, eW0, eW1, eW2,
                                                 wsWcT, wsW1T, wsWt0, wsWt1, wsWt2);
    k_fused<<<dim3(256), dim3(768), 0, stream>>>(x0, x1, x2, eb0, eb1, eb2,
                                                 wsWt0, wsWt1, wsWt2, wsWcT,
                                                 affw, Ww, Wh, wsW1T, cb1, cW2, cb2,
                                                 (float*)d_out, pc);
}

// Round 5
// 111.122 us; speedup vs baseline: 1.0778x; 1.0778x over previous
//
#include <hip/hip_runtime.h>
#include <math.h>

#define NJ 8         // odd powers x^1..x^15
#define DEG 15
#define X0f 3.0f
#define NB 4         // batch rows per block
#define NT 384       // threads per block (6 waves)

struct Poly { float c[NJ]; };

#define FMA4(A,S,W) do { (A).x = fmaf((S),(W).x,(A).x); (A).y = fmaf((S),(W).y,(A).y); \
                         (A).z = fmaf((S),(W).z,(A).z); (A).w = fmaf((S),(W).w,(A).w); } while(0)

// ---------------- K0: repack weights ----------------
// WcT[i][m 0..463][32]  (m = seg*152+e', zero pads; rows 456..463 zero)
// W1T[m 0..455][128]
// Wt0[304][152], Wt1[76][152], Wt2[36][152]  (d-major, e-padded, zero pads)
__global__ __launch_bounds__(256) void k_repack(
    const float* __restrict__ Wc, const float* __restrict__ W1,
    const float* __restrict__ eW0, const float* __restrict__ eW1, const float* __restrict__ eW2,
    float* __restrict__ WcT, float* __restrict__ W1T,
    float* __restrict__ Wt0, float* __restrict__ Wt1, float* __restrict__ Wt2) {
    int tid = blockIdx.x * 256 + threadIdx.x;
    int stride = gridDim.x * 256;
    for (int idx = tid; idx < 3 * 464 * 32; idx += stride) {
        int i = idx / (464 * 32); int rem = idx - i * 464 * 32;
        int m = rem >> 5, h = rem & 31;
        float v = 0.f;
        if (m < 456) {
            int seg = m / 152, e = m - seg * 152;
            if (e < 150) v = Wc[((size_t)i * 32 + h) * 450 + seg * 150 + e];
        }
        WcT[idx] = v;
    }
    for (int idx = tid; idx < 456 * 128; idx += stride) {
        int m = idx >> 7, k = idx & 127;
        int seg = m / 152, e = m - seg * 152;
        W1T[idx] = (e < 150) ? W1[k * 450 + seg * 150 + e] : 0.f;
    }
    for (int idx = tid; idx < 304 * 152; idx += stride) {
        int d = idx / 152, e = idx - d * 152;
        Wt0[idx] = (d < 300 && e < 150) ? eW0[e * 300 + d] : 0.f;
    }
    for (int idx = tid; idx < 76 * 152; idx += stride) {
        int d = idx / 152, e = idx - d * 152;
        Wt1[idx] = (d < 74 && e < 150) ? eW1[e * 74 + d] : 0.f;
    }
    for (int idx = tid; idx < 36 * 152; idx += stride) {
        int d = idx / 152, e = idx - d * 152;
        Wt2[idx] = (d < 35 && e < 150) ? eW2[e * 35 + d] : 0.f;
    }
}

// ---------------- K1: fused enc -> attn -> cls. grid 512, block 384, 2 blocks/CU ----------------
__global__ __launch_bounds__(NT, 3) void k_fused(
    const float* __restrict__ x0, const float* __restrict__ x1, const float* __restrict__ x2,
    const float* __restrict__ eb0, const float* __restrict__ eb1, const float* __restrict__ eb2,
    const float* __restrict__ Wt0, const float* __restrict__ Wt1, const float* __restrict__ Wt2,
    const float* __restrict__ WcT,
    const float* __restrict__ affw, const float* __restrict__ Ww, const float* __restrict__ Wh,
    const float* __restrict__ W1T, const float* __restrict__ cb1,
    const float* __restrict__ cW2, const float* __restrict__ cb2,
    float* __restrict__ out, Poly pc) {
    __shared__ __align__(16) float xs[NB * 428];    // x stage; reused as cls hpart
    __shared__ __align__(16) float featf[NB * 468]; // enc outputs; rows reused as hs
    __shared__ __align__(16) float fof[NB * 468];   // attn outputs (cls input)
    __shared__ __align__(16) float wWs[96], wHs[96];

    int tid = threadIdx.x;
    int b0 = blockIdx.x * NB;

    // ---- P0: stage x, small weights, zero feat pads ----
    if (tid < 96) { wWs[tid] = Ww[tid]; wHs[tid] = Wh[tid]; }
    if (tid >= 96 && tid < 144) {
        int q = tid - 96; int b = q / 12, r = q - b * 12;
        featf[b * 468 + 456 + r] = 0.f;
    }
    for (int idx = tid; idx < NB * 75; idx += NT) {
        int b = idx / 75, q = idx - b * 75;
        ((float4*)(xs + b * 428))[q] = ((const float4*)(x0 + (size_t)(b0 + b) * 300))[q];
    }
    for (int idx = tid; idx < NB * 74; idx += NT) {
        int b = idx / 74, d = idx - b * 74;
        xs[b * 428 + 304 + d] = x1[(size_t)(b0 + b) * 74 + d];
    }
    for (int idx = tid; idx < NB * 35; idx += NT) {
        int b = idx / 35, d = idx - b * 35;
        xs[b * 428 + 380 + d] = x2[(size_t)(b0 + b) * 35 + d];
    }
    __syncthreads();

    // ---- P1: encoders. task = (m4 = t>>2, b = t&3); 456 tasks, pure register acc ----
    for (int task = tid; task < NB * 114; task += NT) {
        int m4 = task >> 2, b = task & 3;
        int seg = (m4 >= 76) ? 2 : (m4 >= 38) ? 1 : 0;
        int e4 = m4 - seg * 38;
        const float* eb = seg == 0 ? eb0 : seg == 1 ? eb1 : eb2;
        const float4* W4 = (const float4*)(seg == 0 ? Wt0 : seg == 1 ? Wt1 : Wt2) + e4;
        const float* xb = xs + b * 428 + (seg == 0 ? 0 : seg == 1 ? 304 : 380);
        int D = seg == 0 ? 300 : seg == 1 ? 74 : 35;
        int e = e4 * 4;
        float4 acc;
        acc.x = eb[e];
        acc.y = eb[e + 1];
        acc.z = (e + 2 < 150) ? eb[e + 2] : 0.f;
        acc.w = (e + 3 < 150) ? eb[e + 3] : 0.f;
        #pragma unroll 4
        for (int d = 0; d < D; ++d) { float xv = xb[d]; float4 wv = W4[d * 38]; FMA4(acc, xv, wv); }
        ((float4*)(featf + b * 468))[m4] = acc;
    }
    __syncthreads();

    // ---- P2: attention. wave = (i = w>>1, wp = w&1); lane = hq(3b)|slice(2b)|bh(1b) ----
    {
        int w = tid >> 6;
        int i = w >> 1, wp = w & 1;
        int lane = tid & 63;
        int hq = lane & 7, slice = (lane >> 3) & 3, bh = lane >> 5;
        int b = wp * 2 + bh;
        float aff = affw[i];
        const float4* Wb4 = (const float4*)WcT + (size_t)i * 3712 + hq;
        const float4* frow = (const float4*)(featf + b * 468);

        float4 acc[NJ];
        #pragma unroll
        for (int J = 0; J < NJ; ++J) acc[J] = make_float4(0.f, 0.f, 0.f, 0.f);
        float mx = 0.f;

        int m4lo = slice * 29;
        for (int m4 = m4lo; m4 < m4lo + 29; ++m4) {
            float4 f4 = frow[m4];
            #pragma unroll
            for (int r = 0; r < 4; ++r) {
                float fv = (r == 0) ? f4.x : (r == 1) ? f4.y : (r == 2) ? f4.z : f4.w;
                mx = fmaxf(mx, fabsf(fv));
                float g = aff * fv;
                float g2 = g * g;
                float4 wv = Wb4[(m4 * 4 + r) * 8];
                float p = g;
                FMA4(acc[0], p, wv);
                #pragma unroll
                for (int J = 1; J < NJ; ++J) { p *= g2; FMA4(acc[J], p, wv); }
            }
        }
        // reduce partial M across slice bits (8,16), fold poly coeff
        #pragma unroll
        for (int J = 0; J < NJ; ++J) {
            float cJ = pc.c[J];
            float vx = acc[J].x; vx += __shfl_xor(vx, 8); vx += __shfl_xor(vx, 16);
            float vy = acc[J].y; vy += __shfl_xor(vy, 8); vy += __shfl_xor(vy, 16);
            float vz = acc[J].z; vz += __shfl_xor(vz, 8); vz += __shfl_xor(vz, 16);
            float vw = acc[J].w; vw += __shfl_xor(vw, 8); vw += __shfl_xor(vw, 16);
            acc[J].x = vx * cJ; acc[J].y = vy * cJ; acc[J].z = vz * cJ; acc[J].w = vw * cJ;
        }
        // full-row max for fallback guard: reduce over bits 0..4 (hq + slice)
        mx = fmaxf(mx, __shfl_xor(mx, 1));
        mx = fmaxf(mx, __shfl_xor(mx, 2));
        mx = fmaxf(mx, __shfl_xor(mx, 4));
        mx = fmaxf(mx, __shfl_xor(mx, 8));
        mx = fmaxf(mx, __shfl_xor(mx, 16));
        float gmax = fabsf(aff) * mx;

        // epilogue
        float4 wW4 = ((const float4*)wWs)[i * 8 + hq];
        float4 wH4 = ((const float4*)wHs)[i * 8 + hq];
        int e4lo = slice * 10;
        int e4hi = (slice == 3) ? 38 : (e4lo + 10);
        for (int e4 = e4lo; e4 < e4hi; ++e4) {
            float4 s4 = frow[i * 38 + e4];
            float ores[4];
            #pragma unroll
            for (int r = 0; r < 4; ++r) {
                float s = (r == 0) ? s4.x : (r == 1) ? s4.y : (r == 2) ? s4.z : s4.w;
                float4 a4;
                if (fabsf(s) * gmax <= X0f) {
                    float s2 = s * s, p = s;
                    a4.x = acc[0].x * p; a4.y = acc[0].y * p;
                    a4.z = acc[0].z * p; a4.w = acc[0].w * p;
                    #pragma unroll
                    for (int J = 1; J < NJ; ++J) { p *= s2; FMA4(a4, p, acc[J]); }
                } else {
                    a4 = make_float4(0.f, 0.f, 0.f, 0.f);
                    for (int c = 0; c < 456; ++c) {
                        float t = tanhf(s * aff * featf[b * 468 + c]);
                        float4 wv = Wb4[c * 8];
                        FMA4(a4, t, wv);
                    }
                }
                float hx = fmaxf(fmaf(s, wW4.x, a4.x), 0.f);
                float hy = fmaxf(fmaf(s, wW4.y, a4.y), 0.f);
                float hz = fmaxf(fmaf(s, wW4.z, a4.z), 0.f);
                float hw = fmaxf(fmaf(s, wW4.w, a4.w), 0.f);
                float csum = hx * wH4.x + hy * wH4.y + hz * wH4.z + hw * wH4.w;
                csum += __shfl_xor(csum, 1);
                csum += __shfl_xor(csum, 2);
                csum += __shfl_xor(csum, 4);
                ores[r] = csum + s;
            }
            if (hq == 0)
                ((float4*)(fof + b * 468))[i * 38 + e4] = make_float4(ores[0], ores[1], ores[2], ores[3]);
        }
    }
    __syncthreads();

    // ---- P3: classifier stage 1. cs = tid>>7 (c-slice), b = (tid>>5)&3, k4 = tid&31 ----
    {
        int cs = tid >> 7;
        int rr = tid & 127;
        int b = rr >> 5, k4 = rr & 31;
        const float4* W14 = (const float4*)W1T + k4;
        const float4* fr = (const float4*)(fof + b * 468);
        float4 a = make_float4(0.f, 0.f, 0.f, 0.f);
        int c4lo = cs * 38;
        for (int c4 = c4lo; c4 < c4lo + 38; ++c4) {
            float4 fv = fr[c4];
            float4 w0 = W14[(c4 * 4 + 0) * 32];
            float4 w1 = W14[(c4 * 4 + 1) * 32];
            float4 w2 = W14[(c4 * 4 + 2) * 32];
            float4 w3 = W14[(c4 * 4 + 3) * 32];
            FMA4(a, fv.x, w0);
            FMA4(a, fv.y, w1);
            FMA4(a, fv.z, w2);
            FMA4(a, fv.w, w3);
        }
        ((float4*)xs)[(cs * 4 + b) * 33 + k4] = a;  // xs reused as hpart
    }
    __syncthreads();
    if (tid < 128) {
        int b = tid >> 5, k4 = tid & 31;
        const float4* hp4 = (const float4*)xs;
        float4 v  = hp4[(0 * 4 + b) * 33 + k4];
        float4 v1 = hp4[(1 * 4 + b) * 33 + k4];
        float4 v2 = hp4[(2 * 4 + b) * 33 + k4];
        float4 bias = ((const float4*)cb1)[k4];
        v.x += v1.x + v2.x + bias.x;
        v.y += v1.y + v2.y + bias.y;
        v.z += v1.z + v2.z + bias.z;
        v.w += v1.w + v2.w + bias.w;
        ((float4*)(featf + b * 468))[k4] = v;  // feat row reused as hs[128]
    }
    __syncthreads();
    if (tid < NB * 7) {
        int b = tid / 7, o = tid - (tid / 7) * 7;
        const float* hb = featf + b * 468;
        const float* w2 = cW2 + o * 128;
        float acc = cb2[o];
        #pragma unroll 4
        for (int k = 0; k < 128; ++k) acc = fmaf(hb[k], w2[k], acc);
        out[(size_t)(b0 + b) * 7 + o] = acc;
    }
}

// ---------------- host: Chebyshev fit of tanh on [-3,3], odd monomials ----------------
static void make_poly(float* cf) {
    const double a = 3.0;
    const int NQ = 128;
    const double PI = 3.14159265358979323846;
    double b[DEG + 1];
    for (int k = 0; k <= DEG; ++k) b[k] = 0.0;
    for (int m = 0; m < NQ; ++m) {
        double th = PI * (m + 0.5) / NQ;
        double f = tanh(a * cos(th));
        for (int k = 1; k <= DEG; k += 2)
            b[k] += (2.0 / NQ) * f * cos(k * th);
    }
    double Tp[DEG + 1], Tc[DEG + 1], Tn[DEG + 1], mono[DEG + 1];
    for (int j = 0; j <= DEG; ++j) { Tp[j] = 0; Tc[j] = 0; mono[j] = 0; }
    Tp[0] = 1.0;
    Tc[1] = 1.0;
    for (int j = 0; j <= DEG; ++j) mono[j] += b[1] * Tc[j];
    for (int k = 2; k <= DEG; ++k) {
        for (int j = 0; j <= DEG; ++j) Tn[j] = -Tp[j];
        for (int j = 1; j <= DEG; ++j) Tn[j] += 2.0 * Tc[j - 1];
        for (int j = 0; j <= DEG; ++j) { Tp[j] = Tc[j]; Tc[j] = Tn[j]; }
        if (k & 1) for (int j = 0; j <= DEG; ++j) mono[j] += b[k] * Tc[j];
    }
    for (int J = 0; J < NJ; ++J) {
        int j = 2 * J + 1;
        cf[J] = (float)(mono[j] / pow(a, (double)j));
    }
}

extern "C" void kernel_launch(void* const* d_in, const int* in_sizes, int n_in,
                              void* d_out, int out_size, void* d_ws, size_t ws_size,
                              hipStream_t stream) {
    (void)in_sizes; (void)n_in; (void)out_size; (void)ws_size;
    const float* x0    = (const float*)d_in[0];
    const float* x1    = (const float*)d_in[1];
    const float* x2    = (const float*)d_in[2];
    const float* eW0   = (const float*)d_in[3];
    const float* eb0   = (const float*)d_in[4];
    const float* eW1   = (const float*)d_in[5];
    const float* eb1   = (const float*)d_in[6];
    const float* eW2   = (const float*)d_in[7];
    const float* eb2   = (const float*)d_in[8];
    const float* affw  = (const float*)d_in[9];
    const float* Ww    = (const float*)d_in[10];
    const float* Wc    = (const float*)d_in[11];
    const float* Wh    = (const float*)d_in[12];
    const float* cW1   = (const float*)d_in[13];
    const float* cb1   = (const float*)d_in[14];
    const float* cW2   = (const float*)d_in[15];
    const float* cb2   = (const float*)d_in[16];

    float* ws    = (float*)d_ws;
    float* wsWcT = ws;                 // 3*464*32  = 44544
    float* wsW1T = ws + 44544;         // 456*128   = 58368
    float* wsWt0 = ws + 102912;        // 304*152   = 46208
    float* wsWt1 = ws + 149120;        // 76*152    = 11552
    float* wsWt2 = ws + 160672;        // 36*152    = 5472

    Poly pc;
    make_poly(pc.c);

    k_repack<<<dim3(96), dim3(256), 0, stream>>>(Wc, cW1, eW0, eW1, eW2,
                                                 wsWcT, wsW1T, wsWt0, wsWt1, wsWt2);
    k_fused<<<dim3(512), dim3(NT), 0, stream>>>(x0, x1, x2, eb0, eb1, eb2,
                                                wsWt0, wsWt1, wsWt2, wsWcT,
                                                affw, Ww, Wh, wsW1T, cb1, cW2, cb2,
                                                (float*)d_out, pc);
}